// Round 6
// baseline (38.080 us; speedup 1.0000x reference)
//
#include <hip/hip_runtime.h>
#include <hip/hip_bf16.h>
#include <math.h>

#define Bn 4096
#define Ln 50
#define Cn 100
#define Tn 50000
#define Dn 128
#define H1n 256
#define H2n 128
#define ROWS 16                   // batch rows per mlp block

#define NTBLK (Tn / 4)            // 12500 table-prep blocks (4 waves, 1 row each)
#define NWPREP 384                // (256*256 + 128*256) / 256 weight-prep blocks

typedef __attribute__((ext_vector_type(8))) short short8;
typedef __attribute__((ext_vector_type(4))) float f32x4;

// ---------------------------------------------------------------------------
// Kernel 1: single streaming pass over table:
//   tableB[t] = bf16(table[t]);  tag_score[t] = dot(table[t], Wr[H2:])
// plus W1/W2 cast+transpose blocks at the tail of the grid.
// ---------------------------------------------------------------------------
__global__ __launch_bounds__(256) void prep_kernel(
    const float* __restrict__ table, const float* __restrict__ Wr,
    const float* __restrict__ W1, const float* __restrict__ W2,
    float* __restrict__ tag_score, __hip_bfloat16* __restrict__ tableB,
    __hip_bfloat16* __restrict__ W1T, __hip_bfloat16* __restrict__ W2T) {
  const int blk = blockIdx.x;
  const int tid = threadIdx.x;

  if (blk < NTBLK) {
    const int t = blk * 4 + (tid >> 6);   // one wave per table row
    const int lane = tid & 63;
    const float2 v = *reinterpret_cast<const float2*>(table + (size_t)t * Dn + lane * 2);
    const float2 w = *reinterpret_cast<const float2*>(Wr + H2n + lane * 2);
    __hip_bfloat162 o;
    o.x = __float2bfloat16(v.x);
    o.y = __float2bfloat16(v.y);
    *reinterpret_cast<__hip_bfloat162*>(tableB + (size_t)t * Dn + lane * 2) = o;
    float acc = v.x * w.x + v.y * w.y;
#pragma unroll
    for (int m = 32; m >= 1; m >>= 1) acc += __shfl_xor(acc, m, 64);
    if (lane == 0) tag_score[t] = acc;
  } else {
    int id = (blk - NTBLK) * 256 + tid;
    if (id < H1n * H1n) {
      const int j = id >> 8, k = id & 255;
      W1T[(size_t)j * (2 * Dn) + k] = __float2bfloat16(W1[(size_t)k * H1n + j]);
    } else {
      id -= H1n * H1n;
      const int j = id >> 8, k = id & 255;  // j < 128, k < 256
      W2T[(size_t)j * H1n + k] = __float2bfloat16(W2[(size_t)k * H2n + j]);
    }
  }
}

// ---------------------------------------------------------------------------
// Kernel 2: masked-mean pooling, one block per batch row, 4 waves:
//   wave 0,1 -> user list (even/odd positions); wave 2,3 -> item list.
// Each wave gathers full 256B bf16 rows (bf162 per lane) with 8-deep ILP.
// Partial sums combined across the wave pair via LDS.
// ---------------------------------------------------------------------------
__global__ __launch_bounds__(256) void pool_kernel(
    const int* __restrict__ user_tags, const int* __restrict__ user_len,
    const int* __restrict__ item_tags, const int* __restrict__ item_len,
    const __hip_bfloat16* __restrict__ tableB, __hip_bfloat16* __restrict__ x_out) {
  __shared__ int s_tags[2][Ln];
  __shared__ float2 s_acc[2][64];
  const int b = blockIdx.x;
  const int tid = threadIdx.x;

  if (tid < Ln) s_tags[0][tid] = user_tags[b * Ln + tid];
  else if (tid >= 128 && tid < 128 + Ln) s_tags[1][tid - 128] = item_tags[b * Ln + (tid - 128)];
  __syncthreads();

  const int w = tid >> 6;         // wave 0..3
  const int half = w >> 1;        // 0 = user, 1 = item
  const int par = w & 1;          // position parity handled by this wave
  const int lane = tid & 63;
  const int len = half ? item_len[b] : user_len[b];
  const int* tags = s_tags[half];

  const __hip_bfloat162* base =
      reinterpret_cast<const __hip_bfloat162*>(tableB) + lane;  // + t*64

  float a0 = 0.f, a1 = 0.f;
  int l = par;
  // 8 gathers in flight
  for (; l + 14 < len; l += 16) {
    __hip_bfloat162 v[8];
#pragma unroll
    for (int q = 0; q < 8; ++q) v[q] = base[(size_t)tags[l + 2 * q] * 64];
#pragma unroll
    for (int q = 0; q < 8; ++q) {
      a0 += __bfloat162float(v[q].x);
      a1 += __bfloat162float(v[q].y);
    }
  }
  // 4 in flight
  for (; l + 6 < len; l += 8) {
    __hip_bfloat162 v[4];
#pragma unroll
    for (int q = 0; q < 4; ++q) v[q] = base[(size_t)tags[l + 2 * q] * 64];
#pragma unroll
    for (int q = 0; q < 4; ++q) {
      a0 += __bfloat162float(v[q].x);
      a1 += __bfloat162float(v[q].y);
    }
  }
  for (; l < len; l += 2) {
    const __hip_bfloat162 v = base[(size_t)tags[l] * 64];
    a0 += __bfloat162float(v.x);
    a1 += __bfloat162float(v.y);
  }

  if (par == 1) s_acc[half][lane] = make_float2(a0, a1);
  __syncthreads();
  if (par == 0) {
    a0 += s_acc[half][lane].x;
    a1 += s_acc[half][lane].y;
    const float inv = 1.f / (float)(len > 0 ? len : 1);
    __hip_bfloat162 o;
    o.x = __float2bfloat16(a0 * inv);
    o.y = __float2bfloat16(a1 * inv);
    *reinterpret_cast<__hip_bfloat162*>(
        x_out + (size_t)b * (2 * Dn) + half * Dn + 2 * lane) = o;
  }
}

// ---------------------------------------------------------------------------
// Kernel 3: MFMA MLP + scoring. 512 threads (8 waves), 16 batch rows/block.
// (verified absmax 0.0 — unchanged)
// ---------------------------------------------------------------------------
__global__ __launch_bounds__(512) void mlp_mfma_kernel(
    const __hip_bfloat16* __restrict__ x_in, const __hip_bfloat16* __restrict__ W1T,
    const float* __restrict__ b1, const __hip_bfloat16* __restrict__ W2T,
    const float* __restrict__ b2, const float* __restrict__ Wr,
    const float* __restrict__ br, const float* __restrict__ tag_score,
    const int* __restrict__ candi_tags, float* __restrict__ out) {
  __shared__ __hip_bfloat16 hl[ROWS][H1n + 8];
  __shared__ float s_part[8][ROWS];
  __shared__ float s_mid[ROWS];

  const int b0 = blockIdx.x * ROWS;
  const int tid = threadIdx.x;
  const int lane = tid & 63;
  const int w = tid >> 6;
  const int lr = lane & 15;
  const int lg = lane >> 4;

  short8 a[8];
  {
    const short* xb = reinterpret_cast<const short*>(x_in) +
                      (size_t)(b0 + lr) * (2 * Dn) + 8 * lg;
#pragma unroll
    for (int s = 0; s < 8; ++s) a[s] = *reinterpret_cast<const short8*>(xb + 32 * s);
  }

#pragma unroll
  for (int t = 0; t < 2; ++t) {
    const int n0 = w * 32 + t * 16;
    f32x4 acc = {0.f, 0.f, 0.f, 0.f};
    const short* wb = reinterpret_cast<const short*>(W1T) +
                      (size_t)(n0 + lr) * (2 * Dn) + 8 * lg;
#pragma unroll
    for (int s = 0; s < 8; ++s) {
      const short8 bfr = *reinterpret_cast<const short8*>(wb + 32 * s);
      acc = __builtin_amdgcn_mfma_f32_16x16x32_bf16(a[s], bfr, acc, 0, 0, 0);
    }
    const int col = n0 + lr;
    const float bias = b1[col];
#pragma unroll
    for (int r = 0; r < 4; ++r) {
      const int row = lg * 4 + r;
      hl[row][col] = __float2bfloat16(fmaxf(acc[r] + bias, 0.f));
    }
  }
  __syncthreads();

  {
    const int n0 = w * 16;
    short8 ah[8];
    const short* hb = reinterpret_cast<const short*>(&hl[0][0]) + lr * (H1n + 8) + 8 * lg;
#pragma unroll
    for (int s = 0; s < 8; ++s) ah[s] = *reinterpret_cast<const short8*>(hb + 32 * s);

    f32x4 acc = {0.f, 0.f, 0.f, 0.f};
    const short* wb = reinterpret_cast<const short*>(W2T) + (size_t)(n0 + lr) * H1n + 8 * lg;
#pragma unroll
    for (int s = 0; s < 8; ++s) {
      const short8 bfr = *reinterpret_cast<const short8*>(wb + 32 * s);
      acc = __builtin_amdgcn_mfma_f32_16x16x32_bf16(ah[s], bfr, acc, 0, 0, 0);
    }
    const int col = n0 + lr;
    const float bias = b2[col];
    const float wr = Wr[col];
    float p[4];
#pragma unroll
    for (int r = 0; r < 4; ++r) p[r] = fmaxf(acc[r] + bias, 0.f) * wr;
#pragma unroll
    for (int m = 1; m <= 8; m <<= 1) {
#pragma unroll
      for (int r = 0; r < 4; ++r) p[r] += __shfl_xor(p[r], m, 64);
    }
    if (lr == 0) {
#pragma unroll
      for (int r = 0; r < 4; ++r) s_part[w][lg * 4 + r] = p[r];
    }
  }
  __syncthreads();

  if (tid < ROWS) {
    float v = 0.f;
#pragma unroll
    for (int ww = 0; ww < 8; ++ww) v += s_part[ww][tid];
    s_mid[tid] = v + br[0];
  }
  __syncthreads();

  for (int i = tid; i < ROWS * Cn; i += 512) {
    const int r = i / Cn;
    const int tg = candi_tags[(size_t)b0 * Cn + i];
    const float v = s_mid[r] + tag_score[tg];
    out[(size_t)b0 * Cn + i] = 1.f / (1.f + __expf(-v));
  }
}

extern "C" void kernel_launch(void* const* d_in, const int* in_sizes, int n_in,
                              void* d_out, int out_size, void* d_ws, size_t ws_size,
                              hipStream_t stream) {
  const int* user_tags  = (const int*)d_in[0];
  const int* user_len   = (const int*)d_in[1];
  const int* item_tags  = (const int*)d_in[2];
  const int* item_len   = (const int*)d_in[3];
  const int* candi_tags = (const int*)d_in[4];
  const float* table    = (const float*)d_in[5];
  const float* W1       = (const float*)d_in[6];
  const float* b1       = (const float*)d_in[7];
  const float* W2       = (const float*)d_in[8];
  const float* b2       = (const float*)d_in[9];
  const float* Wr       = (const float*)d_in[10];
  const float* br       = (const float*)d_in[11];
  float* out = (float*)d_out;

  char* ws = (char*)d_ws;
  float* tag_score       = (float*)(ws);                        // 200000 B
  __hip_bfloat16* tableB = (__hip_bfloat16*)(ws + 204800);      // 12.8 MB
  __hip_bfloat16* x_buf  = (__hip_bfloat16*)(ws + 13004800);    // 2 MB
  __hip_bfloat16* W1T    = (__hip_bfloat16*)(ws + 15101952);    // 128 KB
  __hip_bfloat16* W2T    = (__hip_bfloat16*)(ws + 15233024);    // 64 KB

  // K1: table bf16 cast + tag_score (one streaming pass) + weight prep
  prep_kernel<<<NTBLK + NWPREP, 256, 0, stream>>>(
      table, Wr, W1, W2, tag_score, tableB, W1T, W2T);

  // K2: pooling, one block per batch row, 2 waves per list
  pool_kernel<<<Bn, 256, 0, stream>>>(
      user_tags, user_len, item_tags, item_len, tableB, x_buf);

  // K3: MFMA MLP + scoring, 16 rows per block
  mlp_mfma_kernel<<<Bn / ROWS, 512, 0, stream>>>(
      x_buf, W1T, b1, W2T, b2, Wr, br, tag_score, candi_tags, out);
}